// Round 1
// baseline (31.742 us; speedup 1.0000x reference)
//
#include <hip/hip_runtime.h>

// CapsulePooling2D: x (32,64,64,256) f32 -> out (32,32,32,256) f32.
// Entire 3-step reference is local to each (batch, 2x2 spatial block):
//   step>0: n_p = softmax-ish normalize of per-pixel scores within the block
//   a_c    = 0.25 * sum_p n_p * x[p][c]           (avg pool of weighted fm)
//   scale  = 1 / (1 + ||a|| + EPS)                (squash)
//   score_p += scale * sum_c x[p][c] * a_c        (score update)
// Output = a from the 3rd iteration (avg_pool(weighted_fm), no squash).
// One 64-lane wave per block; 4 channels/lane as float4; shfl_xor reductions.

static constexpr float EPS = 1e-7f;

__global__ __launch_bounds__(256) void capsule_pool_kernel(
    const float* __restrict__ x, float* __restrict__ out)
{
    constexpr int H = 64, W = 64, C = 256;
    constexpr int HB = H / 2, WB = W / 2;   // 32 x 32 pooled grid

    const int lane  = threadIdx.x & 63;
    const int waveId = threadIdx.x >> 6;
    const int blk = blockIdx.x * 4 + waveId;      // global 2x2-block id, 0..32767

    const int j = blk & (WB - 1);
    const int i = (blk >> 5) & (HB - 1);
    const int b = blk >> 10;

    const size_t rowStride = (size_t)W * C;
    const size_t base = ((size_t)b * H + 2 * i) * rowStride
                      + (size_t)(2 * j) * C + lane * 4;

    // 4 pixels of the block: (2i,2j) (2i,2j+1) (2i+1,2j) (2i+1,2j+1)
    const float4 xv0 = *(const float4*)(x + base);
    const float4 xv1 = *(const float4*)(x + base + C);
    const float4 xv2 = *(const float4*)(x + base + rowStride);
    const float4 xv3 = *(const float4*)(x + base + rowStride + C);

    float s0 = 0.f, s1 = 0.f, s2 = 0.f, s3 = 0.f;  // per-pixel scores (wave-uniform)
    float4 a;                                       // pooled weighted avg (per-lane 4 ch)

    #pragma unroll
    for (int step = 0; step < 3; ++step) {
        float n0 = 1.f, n1 = 1.f, n2 = 1.f, n3 = 1.f;
        if (step > 0) {
            // normalize_pool_map: within-block softmax-like weights, T=2
            const float m = fmaxf(fmaxf(s0, s1), fmaxf(s2, s3));
            const float e0 = expf((s0 - m) * 0.5f);
            const float e1 = expf((s1 - m) * 0.5f);
            const float e2 = expf((s2 - m) * 0.5f);
            const float e3 = expf((s3 - m) * 0.5f);
            const float inv = 1.f / (0.25f * (e0 + e1 + e2 + e3) + EPS);
            n0 = e0 * inv; n1 = e1 * inv; n2 = e2 * inv; n3 = e3 * inv;
        }
        // a = avg-pool of weighted feature map (this lane's 4 channels)
        a.x = 0.25f * (n0 * xv0.x + n1 * xv1.x + n2 * xv2.x + n3 * xv3.x);
        a.y = 0.25f * (n0 * xv0.y + n1 * xv1.y + n2 * xv2.y + n3 * xv3.y);
        a.z = 0.25f * (n0 * xv0.z + n1 * xv1.z + n2 * xv2.z + n3 * xv3.z);
        a.w = 0.25f * (n0 * xv0.w + n1 * xv1.w + n2 * xv2.w + n3 * xv3.w);

        if (step < 2) {   // step 3's score update is dead code in the reference
            // squash scale: 1/(1 + ||a||_c + EPS), reduce over 256 channels
            float ss = a.x * a.x + a.y * a.y + a.z * a.z + a.w * a.w;
            #pragma unroll
            for (int off = 32; off; off >>= 1) ss += __shfl_xor(ss, off, 64);
            const float scale = 1.f / (1.f + sqrtf(ss) + EPS);

            // score update: score_p += scale * sum_c x[p][c] * a_c
            float p0 = xv0.x * a.x + xv0.y * a.y + xv0.z * a.z + xv0.w * a.w;
            float p1 = xv1.x * a.x + xv1.y * a.y + xv1.z * a.z + xv1.w * a.w;
            float p2 = xv2.x * a.x + xv2.y * a.y + xv2.z * a.z + xv2.w * a.w;
            float p3 = xv3.x * a.x + xv3.y * a.y + xv3.z * a.z + xv3.w * a.w;
            #pragma unroll
            for (int off = 32; off; off >>= 1) {
                p0 += __shfl_xor(p0, off, 64);
                p1 += __shfl_xor(p1, off, 64);
                p2 += __shfl_xor(p2, off, 64);
                p3 += __shfl_xor(p3, off, 64);
            }
            s0 += p0 * scale; s1 += p1 * scale;
            s2 += p2 * scale; s3 += p3 * scale;
        }
    }

    // out[b][i][j][c] = a_c (avg_pool of step-3 weighted fm)
    const size_t obase = (((size_t)b * HB + i) * WB + j) * C + lane * 4;
    *(float4*)(out + obase) = a;
}

extern "C" void kernel_launch(void* const* d_in, const int* in_sizes, int n_in,
                              void* d_out, int out_size, void* d_ws, size_t ws_size,
                              hipStream_t stream) {
    const float* x = (const float*)d_in[0];
    float* out = (float*)d_out;
    // 32*32*32 = 32768 blocks, 4 waves (one block each) per 256-thread workgroup
    capsule_pool_kernel<<<8192, 256, 0, stream>>>(x, out);
}

// Round 2
// 30.491 us; speedup vs baseline: 1.0410x; 1.0410x over previous
//
#include <hip/hip_runtime.h>

// CapsulePooling2D: x (32,64,64,256) f32 -> out (32,32,32,256) f32.
// All work is local to each (batch, 2x2 spatial block). One 64-lane wave
// handles TWO adjacent blocks (lanes 0-31 = block A, 32-63 = block B),
// 8 channels per lane; channel reductions are width-32 shfl_xor butterflies
// (5 stages) serving both blocks simultaneously.

static constexpr float EPS = 1e-7f;

__device__ __forceinline__ float dot4(const float4& u, const float4& v) {
    return u.x * v.x + u.y * v.y + u.z * v.z + u.w * v.w;
}

__global__ __launch_bounds__(256) void capsule_pool_kernel(
    const float* __restrict__ x, float* __restrict__ out)
{
    constexpr int H = 64, W = 64, C = 256;
    constexpr int HB = H / 2, WB = W / 2;   // 32 x 32 pooled grid

    const int lane   = threadIdx.x & 63;
    const int waveId = threadIdx.x >> 6;
    const int half   = lane >> 5;   // which block of the pair
    const int l      = lane & 31;   // lane within half; owns channels 8l..8l+7

    const int pid = blockIdx.x * 4 + waveId;       // block-pair id, 0..16383
    const int jp  = pid & (WB / 2 - 1);            // 0..15 (pair of j's)
    const int i   = (pid >> 4) & (HB - 1);
    const int b   = pid >> 9;
    const int j   = 2 * jp + half;                 // this half's pooled column

    const size_t rowStride = (size_t)W * C;
    const size_t base = ((size_t)b * H + 2 * i) * rowStride
                      + (size_t)(2 * j) * C + l * 8;

    // 4 pixels x 8 channels (2 float4 each): (2i,2j) (2i,2j+1) (2i+1,2j) (2i+1,2j+1)
    const float4 x0a = *(const float4*)(x + base);
    const float4 x0b = *(const float4*)(x + base + 4);
    const float4 x1a = *(const float4*)(x + base + C);
    const float4 x1b = *(const float4*)(x + base + C + 4);
    const float4 x2a = *(const float4*)(x + base + rowStride);
    const float4 x2b = *(const float4*)(x + base + rowStride + 4);
    const float4 x3a = *(const float4*)(x + base + rowStride + C);
    const float4 x3b = *(const float4*)(x + base + rowStride + C + 4);

    float s0 = 0.f, s1 = 0.f, s2 = 0.f, s3 = 0.f;  // per-pixel scores (half-uniform)
    float4 aa, ab;                                  // pooled weighted avg (8 ch/lane)

    #pragma unroll
    for (int step = 0; step < 3; ++step) {
        float n0 = 1.f, n1 = 1.f, n2 = 1.f, n3 = 1.f;
        if (step > 0) {
            // normalize_pool_map: within-block softmax-like weights, T=2
            const float m = fmaxf(fmaxf(s0, s1), fmaxf(s2, s3));
            const float e0 = expf((s0 - m) * 0.5f);
            const float e1 = expf((s1 - m) * 0.5f);
            const float e2 = expf((s2 - m) * 0.5f);
            const float e3 = expf((s3 - m) * 0.5f);
            const float inv = 1.f / (0.25f * (e0 + e1 + e2 + e3) + EPS);
            n0 = e0 * inv; n1 = e1 * inv; n2 = e2 * inv; n3 = e3 * inv;
        }
        // a = avg-pool of weighted feature map (this lane's 8 channels)
        aa.x = 0.25f * (n0 * x0a.x + n1 * x1a.x + n2 * x2a.x + n3 * x3a.x);
        aa.y = 0.25f * (n0 * x0a.y + n1 * x1a.y + n2 * x2a.y + n3 * x3a.y);
        aa.z = 0.25f * (n0 * x0a.z + n1 * x1a.z + n2 * x2a.z + n3 * x3a.z);
        aa.w = 0.25f * (n0 * x0a.w + n1 * x1a.w + n2 * x2a.w + n3 * x3a.w);
        ab.x = 0.25f * (n0 * x0b.x + n1 * x1b.x + n2 * x2b.x + n3 * x3b.x);
        ab.y = 0.25f * (n0 * x0b.y + n1 * x1b.y + n2 * x2b.y + n3 * x3b.y);
        ab.z = 0.25f * (n0 * x0b.z + n1 * x1b.z + n2 * x2b.z + n3 * x3b.z);
        ab.w = 0.25f * (n0 * x0b.w + n1 * x1b.w + n2 * x2b.w + n3 * x3b.w);

        if (step < 2) {   // step 3's score update is dead code in the reference
            // squash scale: 1/(1 + ||a||_c + EPS), reduce over this block's 32 lanes
            float ss = dot4(aa, aa) + dot4(ab, ab);
            #pragma unroll
            for (int off = 16; off; off >>= 1) ss += __shfl_xor(ss, off, 32);
            const float scale = 1.f / (1.f + sqrtf(ss) + EPS);

            // score update: score_p += scale * sum_c x[p][c] * a_c
            float p0 = dot4(x0a, aa) + dot4(x0b, ab);
            float p1 = dot4(x1a, aa) + dot4(x1b, ab);
            float p2 = dot4(x2a, aa) + dot4(x2b, ab);
            float p3 = dot4(x3a, aa) + dot4(x3b, ab);
            #pragma unroll
            for (int off = 16; off; off >>= 1) {
                p0 += __shfl_xor(p0, off, 32);
                p1 += __shfl_xor(p1, off, 32);
                p2 += __shfl_xor(p2, off, 32);
                p3 += __shfl_xor(p3, off, 32);
            }
            s0 += p0 * scale; s1 += p1 * scale;
            s2 += p2 * scale; s3 += p3 * scale;
        }
    }

    // out[b][i][j][c] = a_c (avg_pool of step-3 weighted fm)
    const size_t obase = (((size_t)b * HB + i) * WB + j) * C + l * 8;
    *(float4*)(out + obase)     = aa;
    *(float4*)(out + obase + 4) = ab;
}

extern "C" void kernel_launch(void* const* d_in, const int* in_sizes, int n_in,
                              void* d_out, int out_size, void* d_ws, size_t ws_size,
                              hipStream_t stream) {
    const float* x = (const float*)d_in[0];
    float* out = (float*)d_out;
    // 16384 block-pairs, 4 waves (one pair each) per 256-thread workgroup
    capsule_pool_kernel<<<4096, 256, 0, stream>>>(x, out);
}